// Round 27
// baseline (463.037 us; speedup 1.0000x reference)
//
#include <hip/hip_runtime.h>
#include <hip/hip_bf16.h>

#define Nn 16384
#define Dd 256
#define L2E 1.4426950408889634f
#define LN2 0.6931471805599453f

typedef __attribute__((ext_vector_type(8))) int int8v;
typedef __attribute__((ext_vector_type(16))) float f32x16;
typedef __attribute__((ext_vector_type(2))) float f32x2;

__device__ inline void gload_lds16(const void* g, void* l) {
    __builtin_amdgcn_global_load_lds(
        (const __attribute__((address_space(1))) void*)g,
        (__attribute__((address_space(3))) void*)l, 16, 0, 0);
}

// fp32 -> fp8 e4m3 (HW RNE). A pre-scaled by log2e: epilogue softplus works in
// exp2/log2 domain with no per-element muls.
__global__ __launch_bounds__(256) void cvt_kernel(
        const float4* __restrict__ a, const float4* __restrict__ b,
        int2* __restrict__ oa, int2* __restrict__ ob) {
    int i = blockIdx.x * 256 + threadIdx.x;
    float4 a0 = a[2 * i], a1 = a[2 * i + 1];
    float4 b0 = b[2 * i], b1 = b[2 * i + 1];
    int alo = __builtin_amdgcn_cvt_pk_fp8_f32(a0.x * L2E, a0.y * L2E, 0, false);
    alo     = __builtin_amdgcn_cvt_pk_fp8_f32(a0.z * L2E, a0.w * L2E, alo, true);
    int ahi = __builtin_amdgcn_cvt_pk_fp8_f32(a1.x * L2E, a1.y * L2E, 0, false);
    ahi     = __builtin_amdgcn_cvt_pk_fp8_f32(a1.z * L2E, a1.w * L2E, ahi, true);
    int blo = __builtin_amdgcn_cvt_pk_fp8_f32(b0.x, b0.y, 0, false);
    blo     = __builtin_amdgcn_cvt_pk_fp8_f32(b0.z, b0.w, blo, true);
    int bhi = __builtin_amdgcn_cvt_pk_fp8_f32(b1.x, b1.y, 0, false);
    bhi     = __builtin_amdgcn_cvt_pk_fp8_f32(b1.z, b1.w, bhi, true);
    oa[i] = make_int2(alo, ahi);
    ob[i] = make_int2(blo, bhi);
}

// ds_read_b128 pair from PRECOMPUTED byte offsets (XOR-deswizzle baked in at
// offset-precompute time; buffer base folds into the instruction immediate).
__device__ inline int8v rdoff(const unsigned char* base, int olo, int ohi) {
    int4 lo = *(const int4*)&base[olo];
    int4 hi = *(const int4*)&base[ohi];
    int8v r;
    r[0] = lo.x; r[1] = lo.y; r[2] = lo.z; r[3] = lo.w;
    r[4] = hi.x; r[5] = hi.y; r[6] = hi.z; r[7] = hi.w;
    return r;
}

#define MFMA_(A, B, C) __builtin_amdgcn_mfma_scale_f32_32x32x64_f8f6f4(       \
    (A), (B), (C), 0, 0, 0, 0x7F7F7F7F, 0, 0x7F7F7F7F)

// Fused MX-fp8 GEMM (sim' = log2e * za.zb^T, unit e8m0 scales) + siglip loss.
// R27: 4 waves/SIMD interleave depth (R26 had 2 — the remaining limiter:
// with 2 waves/SIMD one wave's epilogue/ds_read stalls idle the MFMA pipe).
// 1024 thr = 16 waves = 4 waves/SIMD, 1 block/CU (96KB LDS). Block = 128M x
// 1024N, 8 panels of 128 cols statically unrolled, B dbuf 2x32KB, A 32KB
// staged once. Wave tile 32x32 -> ONE f32x16 acc (16 AGPR, single
// generation: spill law). launch_bounds(1024,4) -> 128-reg cap, demand ~90.
// Per-SIMD per panel: MFMA 16x68=1088 cyc vs ds_read 768 cyc -> MFMA-bound
// if 4-way interleave hides VALU/trans/waits.
__global__ __launch_bounds__(1024, 4) void siglip_kernel(
        const unsigned char* __restrict__ ga,   // za*log2e fp8 [16384][256]
        const unsigned char* __restrict__ gb,   // zb fp8 [16384][256]
        const float* __restrict__ bp,           // bias scalar
        float* __restrict__ out) {
    __shared__ unsigned char As[128 * 256];   // 32 KB, full-K A tile
    __shared__ unsigned char Bs0[128 * 256];  // 32 KB, B panel buffer 0
    __shared__ unsigned char Bs1[128 * 256];  // 32 KB, B panel buffer 1
    __shared__ float wsum[16];

    const int tid  = threadIdx.x;
    const int lane = tid & 63;
    const int wid  = tid >> 6;     // 0..15
    const int wm   = wid >> 2;     // 0..3 -> 32-row slice of the 128-row tile
    const int wn   = wid & 3;      // 0..3 -> 32-col slice of the 128-col panel
    const int l31  = lane & 31;
    const int h    = lane >> 5;

    // XCD-chunked bijective swizzle (grid 2048 = 8 XCD x 256); consecutive
    // nid share the A panel (same by) and sweep B -> per-XCD L2 locality.
    const int bid = blockIdx.x;
    const int nid = (bid & 7) * 256 + (bid >> 3);
    const int by  = nid >> 4;      // 0..127  M-tile (128 rows)
    const int bxs = nid & 15;      // 0..15   N-supertile (1024 cols)
    const size_t rowA0 = (size_t)by * 128;
    const int    rB0   = bxs * 1024;

    const float b2 = bp[0] * L2E;
    const int diagblk = (bxs == (by >> 3));
    const int dpan    = by & 7;    // which 128-col panel holds the diagonal

    // ---- stage A once: 2 loads/thread; LDS dest linear, source swizzled ----
#pragma unroll
    for (int p = 0; p < 2; ++p) {
        int c = p * 1024 + tid; int row = c >> 4;
        int scl = (c & 15) ^ (row & 15);
        gload_lds16(&ga[(rowA0 + row) * Dd + scl * 16], &As[c * 16]);
    }

    // ---- B staging: 2 running source pointers, advanced 32768 B per panel ----
    const unsigned char* gp[2];
#pragma unroll
    for (int p = 0; p < 2; ++p) {
        int c = p * 1024 + tid; int row = c >> 4;
        int scl = (c & 15) ^ (row & 15);
        gp[p] = &gb[(size_t)(rB0 + row) * 256 + scl * 16];
    }
#define STAGE_ADV(BBUF)                                                       \
    {                                                                         \
        _Pragma("unroll")                                                     \
        for (int p = 0; p < 2; ++p) {                                         \
            gload_lds16(gp[p], &(BBUF)[(p * 1024 + tid) * 16]);               \
            gp[p] += 32768;                                                   \
        }                                                                     \
    }
    STAGE_ADV(Bs0)   // panel 0
    STAGE_ADV(Bs1)   // panel 1

    // ---- precompute ALL LDS read offsets (XOR-deswizzle baked in) ----
    int offA[8], offB[8];
    {
        int ra = wm * 32 + l31, xa = ra & 15;
        int rb = wn * 32 + l31, xb = rb & 15;
#pragma unroll
        for (int s = 0; s < 4; ++s) {
            int cb = s * 4 + h * 2;
            offA[s * 2 + 0] = ra * 256 + ((cb) ^ xa) * 16;
            offA[s * 2 + 1] = ra * 256 + ((cb + 1) ^ xa) * 16;
            offB[s * 2 + 0] = rb * 256 + ((cb) ^ xb) * 16;
            offB[s * 2 + 1] = rb * 256 + ((cb + 1) ^ xb) * 16;
        }
    }

    // read-only bias accumulator: C operand of every panel's first MFMA.
    f32x16 bias_acc;
#pragma unroll
    for (int q = 0; q < 16; ++q) bias_acc[q] = -b2;

    // outstanding: A(2)+B0(2)+B1(2)=6; wait to <=2 -> A and B0 landed.
    asm volatile("s_waitcnt vmcnt(2)" ::: "memory");
    __builtin_amdgcn_s_barrier();
    asm volatile("" ::: "memory");

    f32x2 sm = {0.f, 0.f}, se = {0.f, 0.f};
    float ld = 0.f;

    // ---- one panel: compute (zero addr VALU) -> barrier -> stage ->
    //      packed epilogue (overlaps stage flight) ----
#define PANEL(BBUF, T, DO_STAGE)                                              \
    {                                                                         \
        f32x16 acc;                                                           \
        {                                                                     \
            int8v aF = rdoff(As, offA[0], offA[1]);                           \
            int8v bF = rdoff(BBUF, offB[0], offB[1]);                         \
            acc = MFMA_(aF, bF, bias_acc);                                    \
        }                                                                     \
        _Pragma("unroll")                                                     \
        for (int s = 1; s < 4; ++s) {                                         \
            int8v aF = rdoff(As, offA[s * 2 + 0], offA[s * 2 + 1]);           \
            int8v bF = rdoff(BBUF, offB[s * 2 + 0], offB[s * 2 + 1]);         \
            acc = MFMA_(aF, bF, acc);                                         \
        }                                                                     \
        asm volatile("" ::: "memory");                                        \
        __builtin_amdgcn_s_barrier();                                         \
        asm volatile("" ::: "memory");                                        \
        if (DO_STAGE) STAGE_ADV(BBUF)                                         \
        _Pragma("unroll")                                                     \
        for (int q = 0; q < 16; q += 2) {                                     \
            f32x2 yv = {acc[q], acc[q + 1]};                                  \
            f32x2 mv = {fmaxf(yv[0], 0.f), fmaxf(yv[1], 0.f)};                \
            sm += mv;                                                         \
            f32x2 ev = {__builtin_amdgcn_exp2f(-fabsf(yv[0])),                \
                        __builtin_amdgcn_exp2f(-fabsf(yv[1]))};               \
            se += ev;                                                         \
        }                                                                     \
        if (diagblk && (T) == dpan && wm == wn) {                             \
            _Pragma("unroll")                                                 \
            for (int q = 0; q < 16; ++q) {                                    \
                int rq = (q & 3) + 8 * (q >> 2) + 4 * h;                      \
                if (rq == l31) {                                              \
                    float y  = acc[q];                                        \
                    float u  = -(y + 2.f * b2);                               \
                    float ey = __builtin_amdgcn_exp2f(-fabsf(y));             \
                    float eu = __builtin_amdgcn_exp2f(-fabsf(u));             \
                    ld += (LN2 * fmaxf(u, 0.f) + eu) -                        \
                          (LN2 * fmaxf(y, 0.f) + ey);                         \
                }                                                             \
            }                                                                 \
        }                                                                     \
    }

#define WAIT2  asm volatile("s_waitcnt vmcnt(2)" ::: "memory");               \
               __builtin_amdgcn_s_barrier(); asm volatile("" ::: "memory");
#define WAIT0  asm volatile("s_waitcnt vmcnt(0)" ::: "memory");               \
               __builtin_amdgcn_s_barrier(); asm volatile("" ::: "memory");

    // ---- 8 panels, statically unrolled (static buffers, zero loop VALU) ----
    PANEL(Bs0, 0, 1)  WAIT2
    PANEL(Bs1, 1, 1)  WAIT2
    PANEL(Bs0, 2, 1)  WAIT2
    PANEL(Bs1, 3, 1)  WAIT2
    PANEL(Bs0, 4, 1)  WAIT2
    PANEL(Bs1, 5, 1)  WAIT2
    PANEL(Bs0, 6, 0)  WAIT0
    PANEL(Bs1, 7, 0)

    // v = ln2*Σm + Σe + diag
    float v = fmaf(LN2, sm[0] + sm[1], se[0] + se[1] + ld);

    // wave reduce then block reduce
#pragma unroll
    for (int off = 32; off; off >>= 1)
        v += __shfl_down(v, off);
    if (lane == 0) wsum[wid] = v;
    __syncthreads();
    if (tid == 0) {
        float t = 0.f;
#pragma unroll
        for (int w = 0; w < 16; ++w) t += wsum[w];
        atomicAdd(out, t * (1.0f / ((float)Nn * (float)Nn)));
    }
#undef STAGE_ADV
#undef PANEL
#undef WAIT2
#undef WAIT0
}

extern "C" void kernel_launch(void* const* d_in, const int* in_sizes, int n_in,
                              void* d_out, int out_size, void* d_ws, size_t ws_size,
                              hipStream_t stream) {
    const float* za   = (const float*)d_in[0];
    const float* zb   = (const float*)d_in[1];
    const float* bias = (const float*)d_in[2];

    unsigned char* wa = (unsigned char*)d_ws;
    unsigned char* wb = wa + (size_t)Nn * Dd;

    // zero the output accumulator (harness does not re-poison between replays)
    hipMemsetAsync(d_out, 0, sizeof(float), stream);

    // fp32 -> fp8 pre-pass (A pre-scaled by log2e)
    cvt_kernel<<<dim3(Nn * Dd / 2048), 256, 0, stream>>>(
        (const float4*)za, (const float4*)zb, (int2*)wa, (int2*)wb);

    // fused GEMM + loss: 128 M-tiles x 16 N-supertiles = 2048 blocks, 1024 thr
    siglip_kernel<<<dim3(2048), 1024, 0, stream>>>(wa, wb, bias, (float*)d_out);
}

// Round 28
// 116.593 us; speedup vs baseline: 3.9714x; 3.9714x over previous
//
#include <hip/hip_runtime.h>
#include <hip/hip_bf16.h>

#define Nn 16384
#define Dd 256
#define L2E 1.4426950408889634f
#define LN2 0.6931471805599453f

typedef __attribute__((ext_vector_type(8))) int int8v;
typedef __attribute__((ext_vector_type(16))) float f32x16;
typedef __attribute__((ext_vector_type(2))) float f32x2;

__device__ inline void gload_lds16(const void* g, void* l) {
    __builtin_amdgcn_global_load_lds(
        (const __attribute__((address_space(1))) void*)g,
        (__attribute__((address_space(3))) void*)l, 16, 0, 0);
}

// fp32 -> fp8 e4m3 (HW RNE). A pre-scaled by log2e: epilogue softplus works in
// exp2/log2 domain with no per-element muls.
__global__ __launch_bounds__(256) void cvt_kernel(
        const float4* __restrict__ a, const float4* __restrict__ b,
        int2* __restrict__ oa, int2* __restrict__ ob) {
    int i = blockIdx.x * 256 + threadIdx.x;
    float4 a0 = a[2 * i], a1 = a[2 * i + 1];
    float4 b0 = b[2 * i], b1 = b[2 * i + 1];
    int alo = __builtin_amdgcn_cvt_pk_fp8_f32(a0.x * L2E, a0.y * L2E, 0, false);
    alo     = __builtin_amdgcn_cvt_pk_fp8_f32(a0.z * L2E, a0.w * L2E, alo, true);
    int ahi = __builtin_amdgcn_cvt_pk_fp8_f32(a1.x * L2E, a1.y * L2E, 0, false);
    ahi     = __builtin_amdgcn_cvt_pk_fp8_f32(a1.z * L2E, a1.w * L2E, ahi, true);
    int blo = __builtin_amdgcn_cvt_pk_fp8_f32(b0.x, b0.y, 0, false);
    blo     = __builtin_amdgcn_cvt_pk_fp8_f32(b0.z, b0.w, blo, true);
    int bhi = __builtin_amdgcn_cvt_pk_fp8_f32(b1.x, b1.y, 0, false);
    bhi     = __builtin_amdgcn_cvt_pk_fp8_f32(b1.z, b1.w, bhi, true);
    oa[i] = make_int2(alo, ahi);
    ob[i] = make_int2(blo, bhi);
}

// ds_read_b128 pair from PRECOMPUTED byte offsets (XOR-deswizzle baked in at
// offset-precompute time; buffer base folds into the instruction immediate).
__device__ inline int8v rdoff(const unsigned char* base, int olo, int ohi) {
    int4 lo = *(const int4*)&base[olo];
    int4 hi = *(const int4*)&base[ohi];
    int8v r;
    r[0] = lo.x; r[1] = lo.y; r[2] = lo.z; r[3] = lo.w;
    r[4] = hi.x; r[5] = hi.y; r[6] = hi.z; r[7] = hi.w;
    return r;
}

#define MFMA_(A, B, C) __builtin_amdgcn_mfma_scale_f32_32x32x64_f8f6f4(       \
    (A), (B), (C), 0, 0, 0, 0x7F7F7F7F, 0, 0x7F7F7F7F)

// Fused MX-fp8 GEMM (sim' = log2e * za.zb^T, unit e8m0 scales) + siglip loss.
// TERMINAL KERNEL (R26, 116.7us — best of 27 rounds). Structure: persistent-A
// pipelined-B, 256 thr = 4 waves, 2 blocks/CU co-resident (65.5KB LDS,
// launch_bounds(256,2)). Session-established allocator laws on gfx950/hipcc:
//  - exactly ONE live acc generation (2-gen spills 8/8: R8/9/12/13/14/19/21,
//    any size, despite sched fences / AGPR pins);
//  - unified cap = 512/(waves/SIMD), arch side = cap/2: 4 waves/SIMD -> 64
//    arch regs -> spill (R27); 2 waves/SIMD at 256-thr blocks is optimal;
//  - barriers fence scheduler regions (epilogue can't fill MFMA gaps, R20 vs
//    R22: merging regions extends liveness -> spill);
//  - cross-block co-residency helps only ~4% (R24), smaller tiles hurt (R11).
// Block = 128Mx1024N (16 panels of 64 cols). A[128][256B]=32KB staged once;
// B dbuf 2x16KB, 2 panels ahead, counted vmcnt(4), vmcnt(0) only at tail.
// All LDS read offsets precomputed (XOR-16 swizzle baked in, zero conflicts);
// B staged via 4 running pointers (+16KB/panel); bias folded into MFMA C
// operand via read-only bias_acc; packed pk_max/exp2(-|y|) epilogue.
// Per R26 counters: MFMA-busy ~29us = the MX-fp8 dense floor for 137.4 GFLOP.
__global__ __launch_bounds__(256, 2) void siglip_kernel(
        const unsigned char* __restrict__ ga,   // za*log2e fp8 [16384][256]
        const unsigned char* __restrict__ gb,   // zb fp8 [16384][256]
        const float* __restrict__ bp,           // bias scalar
        float* __restrict__ out) {
    __shared__ unsigned char As[128 * 256];   // 32 KB, full-K A tile
    __shared__ unsigned char Bs0[64 * 256];   // 16 KB, B panel buffer 0
    __shared__ unsigned char Bs1[64 * 256];   // 16 KB, B panel buffer 1
    __shared__ float wsum[4];

    const int tid  = threadIdx.x;
    const int lane = tid & 63;
    const int wid  = tid >> 6;     // 0..3
    const int wm   = wid >> 1;     // 0..1 -> 64-row slice of the 128-row tile
    const int wn   = wid & 1;      // 0..1 -> 32-col slice of the 64-col panel
    const int l31  = lane & 31;
    const int h    = lane >> 5;

    // XCD-chunked bijective swizzle (grid 2048 = 8 XCD x 256); consecutive
    // nid share the A panel (same by) and sweep B -> per-XCD L2 locality.
    const int bid = blockIdx.x;
    const int nid = (bid & 7) * 256 + (bid >> 3);
    const int by  = nid >> 4;      // 0..127  M-tile (128 rows)
    const int bxs = nid & 15;      // 0..15   N-supertile (1024 cols)
    const size_t rowA0 = (size_t)by * 128;
    const int    rB0   = bxs * 1024;

    const float b2 = bp[0] * L2E;
    const int diagblk = (bxs == (by >> 3));
    const int dby7    = by & 7;    // which panel-pair holds this block's diag

    // ---- stage A once: 8 loads/thread; LDS dest linear, source swizzled ----
#pragma unroll
    for (int p = 0; p < 8; ++p) {
        int c = p * 256 + tid; int row = c >> 4;
        int scl = (c & 15) ^ (row & 15);
        gload_lds16(&ga[(rowA0 + row) * Dd + scl * 16], &As[c * 16]);
    }

    // ---- B staging: 4 running source pointers, advanced 16384 B per panel ----
    const unsigned char* gp[4];
#pragma unroll
    for (int p = 0; p < 4; ++p) {
        int c = p * 256 + tid; int row = c >> 4;
        int scl = (c & 15) ^ (row & 15);
        gp[p] = &gb[(size_t)(rB0 + row) * 256 + scl * 16];
    }
#define STAGE_ADV(BBUF)                                                       \
    {                                                                         \
        _Pragma("unroll")                                                     \
        for (int p = 0; p < 4; ++p) {                                         \
            gload_lds16(gp[p], &(BBUF)[(p * 256 + tid) * 16]);                \
            gp[p] += 16384;                                                   \
        }                                                                     \
    }
    STAGE_ADV(Bs0)   // panel 0
    STAGE_ADV(Bs1)   // panel 1

    // ---- precompute ALL LDS read offsets (XOR-deswizzle baked in) ----
    int offA[16], offB[8];
#pragma unroll
    for (int s = 0; s < 4; ++s) {
        int cb = s * 4 + h * 2;
#pragma unroll
        for (int mf = 0; mf < 2; ++mf) {
            int rr = wm * 64 + mf * 32 + l31;
            int x  = rr & 15;
            offA[s * 4 + mf * 2 + 0] = rr * 256 + ((cb) ^ x) * 16;
            offA[s * 4 + mf * 2 + 1] = rr * 256 + ((cb + 1) ^ x) * 16;
        }
        int rb = wn * 32 + l31;
        int xb = rb & 15;
        offB[s * 2 + 0] = rb * 256 + ((cb) ^ xb) * 16;
        offB[s * 2 + 1] = rb * 256 + ((cb + 1) ^ xb) * 16;
    }

    // read-only bias accumulator: C operand of every panel's first MFMA.
    f32x16 bias_acc;
#pragma unroll
    for (int q = 0; q < 16; ++q) bias_acc[q] = -b2;

    // outstanding: A(8)+B0(4)+B1(4)=16; wait to <=4 -> A and B0 landed.
    asm volatile("s_waitcnt vmcnt(4)" ::: "memory");
    __builtin_amdgcn_s_barrier();
    asm volatile("" ::: "memory");

    f32x2 sm = {0.f, 0.f}, se = {0.f, 0.f};
    float ld = 0.f;

    // ---- one panel: compute (zero addr VALU) -> barrier -> stage ->
    //      packed epilogue (overlaps stage flight) ----
#define PANEL(BBUF, T, DO_STAGE)                                              \
    {                                                                         \
        f32x16 acc[2];                                                        \
        {                                                                     \
            int8v aF0 = rdoff(As, offA[0], offA[1]);                          \
            int8v aF1 = rdoff(As, offA[2], offA[3]);                          \
            int8v bF  = rdoff(BBUF, offB[0], offB[1]);                        \
            acc[0] = MFMA_(aF0, bF, bias_acc);                                \
            acc[1] = MFMA_(aF1, bF, bias_acc);                                \
        }                                                                     \
        _Pragma("unroll")                                                     \
        for (int s = 1; s < 4; ++s) {                                         \
            int8v aF0 = rdoff(As, offA[s * 4 + 0], offA[s * 4 + 1]);          \
            int8v aF1 = rdoff(As, offA[s * 4 + 2], offA[s * 4 + 3]);          \
            int8v bF  = rdoff(BBUF, offB[s * 2 + 0], offB[s * 2 + 1]);        \
            acc[0] = MFMA_(aF0, bF, acc[0]);                                  \
            acc[1] = MFMA_(aF1, bF, acc[1]);                                  \
        }                                                                     \
        asm volatile("" ::: "memory");                                        \
        __builtin_amdgcn_s_barrier();                                         \
        asm volatile("" ::: "memory");                                        \
        if (DO_STAGE) STAGE_ADV(BBUF)                                         \
        _Pragma("unroll")                                                     \
        for (int mf = 0; mf < 2; ++mf)                                        \
            _Pragma("unroll")                                                 \
            for (int q = 0; q < 16; q += 2) {                                 \
                f32x2 yv = {acc[mf][q], acc[mf][q + 1]};                      \
                f32x2 mv = {fmaxf(yv[0], 0.f), fmaxf(yv[1], 0.f)};            \
                sm += mv;                                                     \
                f32x2 ev = {__builtin_amdgcn_exp2f(-fabsf(yv[0])),            \
                            __builtin_amdgcn_exp2f(-fabsf(yv[1]))};           \
                se += ev;                                                     \
            }                                                                 \
        if (diagblk && ((T) >> 1) == dby7 && wm == ((T) & 1)) {               \
            const int mfd = wn;                                               \
            _Pragma("unroll")                                                 \
            for (int q = 0; q < 16; ++q) {                                    \
                int rq = (q & 3) + 8 * (q >> 2) + 4 * h;                      \
                if (rq == l31) {                                              \
                    float y  = acc[mfd][q];                                   \
                    float u  = -(y + 2.f * b2);                               \
                    float ey = __builtin_amdgcn_exp2f(-fabsf(y));             \
                    float eu = __builtin_amdgcn_exp2f(-fabsf(u));             \
                    ld += (LN2 * fmaxf(u, 0.f) + eu) -                        \
                          (LN2 * fmaxf(y, 0.f) + ey);                         \
                }                                                             \
            }                                                                 \
        }                                                                     \
    }

#define WAIT4  asm volatile("s_waitcnt vmcnt(4)" ::: "memory");               \
               __builtin_amdgcn_s_barrier(); asm volatile("" ::: "memory");
#define WAIT0  asm volatile("s_waitcnt vmcnt(0)" ::: "memory");               \
               __builtin_amdgcn_s_barrier(); asm volatile("" ::: "memory");

    // ---- panels 0..13 (2x unrolled: static buffers), tail 14/15 ----
#pragma unroll 1
    for (int tt = 0; tt < 7; ++tt) {
        PANEL(Bs0, tt * 2, 1)
        WAIT4
        PANEL(Bs1, tt * 2 + 1, 1)
        WAIT4
    }
    PANEL(Bs0, 14, 0)
    WAIT0
    PANEL(Bs1, 15, 0)

    // v = ln2*Σm + Σe + diag
    float v = fmaf(LN2, sm[0] + sm[1], se[0] + se[1] + ld);

    // wave reduce then block reduce
#pragma unroll
    for (int off = 32; off; off >>= 1)
        v += __shfl_down(v, off);
    if (lane == 0) wsum[wid] = v;
    __syncthreads();
    if (tid == 0) {
        float t = wsum[0] + wsum[1] + wsum[2] + wsum[3];
        atomicAdd(out, t * (1.0f / ((float)Nn * (float)Nn)));
    }
#undef STAGE_ADV
#undef PANEL
#undef WAIT4
#undef WAIT0
}

extern "C" void kernel_launch(void* const* d_in, const int* in_sizes, int n_in,
                              void* d_out, int out_size, void* d_ws, size_t ws_size,
                              hipStream_t stream) {
    const float* za   = (const float*)d_in[0];
    const float* zb   = (const float*)d_in[1];
    const float* bias = (const float*)d_in[2];

    unsigned char* wa = (unsigned char*)d_ws;
    unsigned char* wb = wa + (size_t)Nn * Dd;

    // zero the output accumulator (harness does not re-poison between replays)
    hipMemsetAsync(d_out, 0, sizeof(float), stream);

    // fp32 -> fp8 pre-pass (A pre-scaled by log2e)
    cvt_kernel<<<dim3(Nn * Dd / 2048), 256, 0, stream>>>(
        (const float4*)za, (const float4*)zb, (int2*)wa, (int2*)wb);

    // fused GEMM + loss: 128 M-tiles x 16 N-supertiles = 2048 blocks, 256 thr
    siglip_kernel<<<dim3(2048), 256, 0, stream>>>(wa, wb, bias, (float*)d_out);
}